// Round 1
// baseline (636.946 us; speedup 1.0000x reference)
//
#include <hip/hip_runtime.h>
#include <hip/hip_bf16.h>

#define B_TOT 131072
#define D     32
#define H1    50
#define QF    528     // tril feature count
#define H2    700
#define KP    544     // quad K padded to 17*32
#define NPH   768     // H2 padded to 8 waves * 96
#define W2B_STRIDE 800  // W2bT k-stride (>= 720+64, 16B-aligned)

typedef __attribute__((ext_vector_type(8))) short  short8x;
typedef __attribute__((ext_vector_type(4))) float  floatx4;

static __device__ __forceinline__ unsigned short f2bf(float f) {
    __hip_bfloat16 h = __float2bfloat16(f);   // RNE
    return __builtin_bit_cast(unsigned short, h);
}

static __device__ __forceinline__ float tanh_fast(float x) {
    float xc = fminf(15.f, fmaxf(-15.f, x));
    float e  = __expf(2.f * xc);
    return 1.f - 2.f * __builtin_amdgcn_rcpf(e + 1.f);
}

// ---------------- prep: convert/pad weights into workspace ----------------
// W2aT[NPH][KP] bf16 : W2aT[c][k] = W2a[k][c] (zeros for c>=700 or k>=528)
// W2bT[32][W2B_STRIDE] bf16 : W2bT[c][k] = W2b[k][c] (zeros k>=700)
// b2ap[NPH] f32 : padded b2a
__global__ void prep_kernel(const float* __restrict__ W2a, const float* __restrict__ b2a,
                            const float* __restrict__ W2b,
                            unsigned short* __restrict__ W2aT,
                            unsigned short* __restrict__ W2bT,
                            float* __restrict__ b2ap) {
    int idx = blockIdx.x * 256 + threadIdx.x;
    const int N1 = NPH * KP;            // 417792
    const int N2 = 32 * W2B_STRIDE;     // 25600
    if (idx < N1) {
        int c = idx / KP, k = idx - c * KP;
        float v = (c < H2 && k < QF) ? W2a[k * H2 + c] : 0.f;
        W2aT[idx] = f2bf(v);
    } else if (idx < N1 + N2) {
        int j = idx - N1;
        int c = j / W2B_STRIDE, k = j - c * W2B_STRIDE;
        float v = (k < H2) ? W2b[k * D + c] : 0.f;
        W2bT[j] = f2bf(v);
    } else if (idx < N1 + N2 + NPH) {
        int k = idx - N1 - N2;
        b2ap[k] = (k < H2) ? b2a[k] : 0.f;
    }
}

// ---------------- fused main kernel ----------------
__global__ __launch_bounds__(512, 2) void fused_kernel(
    const float* __restrict__ y,   const float* __restrict__ W1a,
    const float* __restrict__ b1a, const float* __restrict__ W1b,
    const float* __restrict__ b1b, const float* __restrict__ b2b,
    const unsigned short* __restrict__ W2aT, const unsigned short* __restrict__ W2bT,
    const float* __restrict__ b2ap, float* __restrict__ out) {

    __shared__ float          yls[64][36];     // y tile (stride 36: float4-aligned)
    __shared__ unsigned short quadls[64][552]; // bf16 quad, K padded to 544 (+8 bank pad)
    __shared__ float          h1ls[64][51];    // net1 hidden
    __shared__ float          outls[64][36];   // output accumulator
    __shared__ unsigned short hst[8][16][72];  // per-wave h re-stage tile

    const int tid  = threadIdx.x;
    const int lane = tid & 63;
    const int w    = tid >> 6;      // wave 0..7
    const int l15  = lane & 15;
    const int lg   = lane >> 4;     // 0..3
    const int row0 = blockIdx.x * 64;

    // ---- Phase A: load y tile, zero hst pad cols ----
    {
        int e = tid * 4;                 // 2048 floats total
        int r = e >> 5, c = e & 31;
        floatx4 v = *reinterpret_cast<const floatx4*>(y + (row0 + r) * D + c);
        *reinterpret_cast<floatx4*>(&yls[r][c]) = v;
    }
    for (int e = tid; e < 8 * 16 * 24; e += 512) {
        int ww = e / 384, rr = (e / 24) & 15, cc = 48 + (e % 24);
        hst[ww][rr][cc] = 0;
    }
    __syncthreads();

    // ---- Phase B: build quad (bf16) + net1 hidden ----
    #pragma unroll
    for (int s = 0; s < 4; ++s) {
        int task = tid + s * 512;        // (row, i) : 64*32 tasks
        int r = task >> 5, i = task & 31;
        int base = (i * (i + 1)) >> 1;
        float yi = yls[r][i];
        for (int j4 = 0; j4 <= i; j4 += 4) {
            floatx4 yv = *reinterpret_cast<const floatx4*>(&yls[r][j4]);
            #pragma unroll
            for (int jj = 0; jj < 4; ++jj) {
                int j = j4 + jj;
                if (j <= i) quadls[r][base + j] = f2bf(yi * yv[jj]);
            }
        }
    }
    for (int e = tid; e < 64 * 16; e += 512)   // zero K-pad 528..543
        quadls[e >> 4][528 + (e & 15)] = 0;

    if (tid < 208) {                     // net1 hidden: 16 row-groups x 13 col-groups
        int rowg = tid / 13, jg = tid - rowg * 13;
        int r0 = rowg * 4, c0 = jg * 4;
        int lim = (c0 + 4 <= H1) ? 4 : (H1 - c0);
        float acc[4][4];
        #pragma unroll
        for (int rr = 0; rr < 4; ++rr)
            #pragma unroll
            for (int jj = 0; jj < 4; ++jj)
                acc[rr][jj] = (jj < lim) ? b1a[c0 + jj] : 0.f;
        for (int i = 0; i < D; ++i) {
            float wv[4];
            #pragma unroll
            for (int jj = 0; jj < 4; ++jj)
                wv[jj] = (jj < lim) ? W1a[i * H1 + c0 + jj] : 0.f;
            #pragma unroll
            for (int rr = 0; rr < 4; ++rr) {
                float yv = yls[r0 + rr][i];
                #pragma unroll
                for (int jj = 0; jj < 4; ++jj) acc[rr][jj] += yv * wv[jj];
            }
        }
        #pragma unroll
        for (int rr = 0; rr < 4; ++rr)
            #pragma unroll
            for (int jj = 0; jj < 4; ++jj)
                if (jj < lim) h1ls[r0 + rr][c0 + jj] = tanh_fast(acc[rr][jj]);
    }
    __syncthreads();

    // ---- Phase C: out1 + all output biases into outls ----
    {
        int r = tid >> 3, c0 = (tid & 7) * 4;
        floatx4 acc;
        #pragma unroll
        for (int jj = 0; jj < 4; ++jj) acc[jj] = b1b[c0 + jj] + b2b[c0 + jj];
        for (int k = 0; k < H1; ++k) {
            float hv = h1ls[r][k];
            floatx4 wv = *reinterpret_cast<const floatx4*>(W1b + k * D + c0);
            #pragma unroll
            for (int jj = 0; jj < 4; ++jj) acc[jj] += hv * wv[jj];
        }
        *reinterpret_cast<floatx4*>(&outls[r][c0]) = acc;
    }
    __syncthreads();

    // ---- Main: wave w owns hidden cols [w*96, w*96+96), two halves of 48 ----
    floatx4 o2[4][2];
    #pragma unroll
    for (int m = 0; m < 4; ++m)
        #pragma unroll
        for (int of = 0; of < 2; ++of) o2[m][of] = (floatx4){0.f, 0.f, 0.f, 0.f};

    for (int half = 0; half < 2; ++half) {
        const int hb = w * 96 + half * 48;
        floatx4 hacc[4][3];
        #pragma unroll
        for (int m = 0; m < 4; ++m)
            #pragma unroll
            for (int nf = 0; nf < 3; ++nf) hacc[m][nf] = (floatx4){0.f, 0.f, 0.f, 0.f};

        const unsigned short* bpt = W2aT + (hb + l15) * KP + lg * 8;

        short8x b[3];
        #pragma unroll
        for (int nf = 0; nf < 3; ++nf)
            b[nf] = *reinterpret_cast<const short8x*>(bpt + nf * 16 * KP);

        #pragma unroll
        for (int k = 0; k < 17; ++k) {
            short8x a[4];
            #pragma unroll
            for (int m = 0; m < 4; ++m)
                a[m] = *reinterpret_cast<const short8x*>(&quadls[m * 16 + l15][k * 32 + lg * 8]);
            short8x bn[3];
            if (k < 16) {
                #pragma unroll
                for (int nf = 0; nf < 3; ++nf)
                    bn[nf] = *reinterpret_cast<const short8x*>(bpt + nf * 16 * KP + (k + 1) * 32);
            }
            #pragma unroll
            for (int m = 0; m < 4; ++m)
                #pragma unroll
                for (int nf = 0; nf < 3; ++nf)
                    hacc[m][nf] = __builtin_amdgcn_mfma_f32_16x16x32_bf16(a[m], b[nf], hacc[m][nf], 0, 0, 0);
            #pragma unroll
            for (int nf = 0; nf < 3; ++nf) b[nf] = bn[nf];
        }

        // epilogue: bias + tanh -> bf16 re-stage -> second GEMM (K=64 incl zero pad)
        float bias[3];
        #pragma unroll
        for (int nf = 0; nf < 3; ++nf) bias[nf] = b2ap[hb + nf * 16 + l15];

        short8x bw[2][2];
        #pragma unroll
        for (int ks = 0; ks < 2; ++ks)
            #pragma unroll
            for (int of = 0; of < 2; ++of)
                bw[ks][of] = *reinterpret_cast<const short8x*>(
                    W2bT + (of * 16 + l15) * W2B_STRIDE + hb + ks * 32 + lg * 8);

        #pragma unroll
        for (int m = 0; m < 4; ++m) {
            #pragma unroll
            for (int nf = 0; nf < 3; ++nf)
                #pragma unroll
                for (int r = 0; r < 4; ++r)
                    hst[w][lg * 4 + r][nf * 16 + l15] =
                        f2bf(tanh_fast(hacc[m][nf][r] + bias[nf]));
            short8x aa0 = *reinterpret_cast<const short8x*>(&hst[w][l15][lg * 8]);
            short8x aa1 = *reinterpret_cast<const short8x*>(&hst[w][l15][32 + lg * 8]);
            o2[m][0] = __builtin_amdgcn_mfma_f32_16x16x32_bf16(aa0, bw[0][0], o2[m][0], 0, 0, 0);
            o2[m][1] = __builtin_amdgcn_mfma_f32_16x16x32_bf16(aa0, bw[0][1], o2[m][1], 0, 0, 0);
            o2[m][0] = __builtin_amdgcn_mfma_f32_16x16x32_bf16(aa1, bw[1][0], o2[m][0], 0, 0, 0);
            o2[m][1] = __builtin_amdgcn_mfma_f32_16x16x32_bf16(aa1, bw[1][1], o2[m][1], 0, 0, 0);
        }
    }

    // ---- deterministic cross-wave reduction into outls ----
    for (int ww = 0; ww < 8; ++ww) {
        if (w == ww) {
            #pragma unroll
            for (int m = 0; m < 4; ++m)
                #pragma unroll
                for (int of = 0; of < 2; ++of)
                    #pragma unroll
                    for (int r = 0; r < 4; ++r)
                        outls[m * 16 + lg * 4 + r][of * 16 + l15] += o2[m][of][r];
        }
        __syncthreads();
    }

    // ---- write out ----
    {
        int e = tid * 4;
        int r = e >> 5, c = e & 31;
        floatx4 v = *reinterpret_cast<const floatx4*>(&outls[r][c]);
        *reinterpret_cast<floatx4*>(out + (row0 + r) * D + c) = v;
    }
}

extern "C" void kernel_launch(void* const* d_in, const int* in_sizes, int n_in,
                              void* d_out, int out_size, void* d_ws, size_t ws_size,
                              hipStream_t stream) {
    const float* y   = (const float*)d_in[1];
    const float* W1a = (const float*)d_in[2];
    const float* b1a = (const float*)d_in[3];
    const float* W1b = (const float*)d_in[4];
    const float* b1b = (const float*)d_in[5];
    const float* W2a = (const float*)d_in[6];
    const float* b2a = (const float*)d_in[7];
    const float* W2b = (const float*)d_in[8];
    const float* b2b = (const float*)d_in[9];

    unsigned short* W2aT = (unsigned short*)d_ws;                          // 835584 B
    unsigned short* W2bT = (unsigned short*)((char*)d_ws + 835584);        //  51200 B
    float*          b2ap = (float*)((char*)d_ws + 835584 + 51200);         //   3072 B

    const int prep_tasks = NPH * KP + 32 * W2B_STRIDE + NPH;               // 444160
    prep_kernel<<<(prep_tasks + 255) / 256, 256, 0, stream>>>(W2a, b2a, W2b, W2aT, W2bT, b2ap);
    fused_kernel<<<B_TOT / 64, 512, 0, stream>>>(y, W1a, b1a, W1b, b1b, b2b,
                                                 W2aT, W2bT, b2ap, (float*)d_out);
}